// Round 1
// baseline (716.527 us; speedup 1.0000x reference)
//
#include <hip/hip_runtime.h>
#include <math.h>

#define DIN 128
#define DOUT 64

// ---------------------------------------------------------------------------
// Kernel 1: support = X @ W   [n_nodes x 128] @ [128 x 64] -> [n_nodes x 64]
// W fully staged in LDS (32 KB), 16 rows of X staged per block (padded to
// avoid bank conflicts). Thread t: row r = t>>4, col-quad c = t&15.
// ---------------------------------------------------------------------------
__global__ __launch_bounds__(256)
void gcn_gemm(const float* __restrict__ x, const float* __restrict__ w,
              float* __restrict__ support, int n_nodes) {
    __shared__ float ws[DIN][DOUT];      // 32 KB
    __shared__ float xs[16][DIN + 4];    // +4 pad -> conflict-free b128 reads

    const int t = threadIdx.x;
    const int base = blockIdx.x * 16;

    // stage W: 8192 floats = 2048 float4, 8 per thread, coalesced
    for (int i = t; i < (DIN * DOUT) / 4; i += 256)
        reinterpret_cast<float4*>(&ws[0][0])[i] =
            reinterpret_cast<const float4*>(w)[i];

    // stage 16 rows of x: 512 float4, 2 per thread, coalesced
    for (int i = t; i < 16 * (DIN / 4); i += 256) {
        int row = i >> 5, kq = i & 31;
        if (base + row < n_nodes) {
            float4 v = reinterpret_cast<const float4*>(x)[
                (size_t)(base + row) * (DIN / 4) + kq];
            *reinterpret_cast<float4*>(&xs[row][kq * 4]) = v;
        }
    }
    __syncthreads();

    const int r = t >> 4;     // 0..15 : row within block
    const int c = t & 15;     // 0..15 : float4 column group

    float4 acc = {0.f, 0.f, 0.f, 0.f};
    #pragma unroll
    for (int k0 = 0; k0 < DIN; k0 += 4) {
        float4 xv = *reinterpret_cast<const float4*>(&xs[r][k0]);
        float4 w0 = *reinterpret_cast<const float4*>(&ws[k0 + 0][c * 4]);
        float4 w1 = *reinterpret_cast<const float4*>(&ws[k0 + 1][c * 4]);
        float4 w2 = *reinterpret_cast<const float4*>(&ws[k0 + 2][c * 4]);
        float4 w3 = *reinterpret_cast<const float4*>(&ws[k0 + 3][c * 4]);
        acc.x += xv.x * w0.x + xv.y * w1.x + xv.z * w2.x + xv.w * w3.x;
        acc.y += xv.x * w0.y + xv.y * w1.y + xv.z * w2.y + xv.w * w3.y;
        acc.z += xv.x * w0.z + xv.y * w1.z + xv.z * w2.z + xv.w * w3.z;
        acc.w += xv.x * w0.w + xv.y * w1.w + xv.z * w2.w + xv.w * w3.w;
    }

    int row = base + r;
    if (row < n_nodes)
        reinterpret_cast<float4*>(support)[(size_t)row * (DOUT / 4) + c] = acc;
}

// ---------------------------------------------------------------------------
// Kernel 2: scatter-add  out[dst] += support[src] * val
// 16 threads per edge, float4 gather + 4 fp32 atomics each.
// ---------------------------------------------------------------------------
__global__ __launch_bounds__(256)
void gcn_scatter(const float* __restrict__ support,
                 const int* __restrict__ esrc, const int* __restrict__ edst,
                 const float* __restrict__ evals, float* __restrict__ out,
                 int n_edges) {
    int tid = blockIdx.x * 256 + threadIdx.x;
    int e = tid >> 4;
    if (e >= n_edges) return;
    int c = tid & 15;
    int s = esrc[e];
    int d = edst[e];
    float v = evals[e];
    float4 m = reinterpret_cast<const float4*>(support)[(size_t)s * (DOUT / 4) + c];
    float* o = out + (size_t)d * DOUT + c * 4;
    atomicAdd(o + 0, m.x * v);
    atomicAdd(o + 1, m.y * v);
    atomicAdd(o + 2, m.z * v);
    atomicAdd(o + 3, m.w * v);
}

// ---------------------------------------------------------------------------
// Kernel 3: out = elu(out + bias), in place, float4
// ---------------------------------------------------------------------------
__global__ __launch_bounds__(256)
void gcn_epilogue(float* __restrict__ out, const float* __restrict__ bias, int n4) {
    int i = blockIdx.x * 256 + threadIdx.x;
    if (i >= n4) return;
    float4 v = reinterpret_cast<float4*>(out)[i];
    float4 b = reinterpret_cast<const float4*>(bias)[i & (DOUT / 4 - 1)];
    v.x += b.x; v.y += b.y; v.z += b.z; v.w += b.w;
    v.x = v.x > 0.f ? v.x : expm1f(v.x);
    v.y = v.y > 0.f ? v.y : expm1f(v.y);
    v.z = v.z > 0.f ? v.z : expm1f(v.z);
    v.w = v.w > 0.f ? v.w : expm1f(v.w);
    reinterpret_cast<float4*>(out)[i] = v;
}

// ---------------------------------------------------------------------------
extern "C" void kernel_launch(void* const* d_in, const int* in_sizes, int n_in,
                              void* d_out, int out_size, void* d_ws, size_t ws_size,
                              hipStream_t stream) {
    const float* x     = (const float*)d_in[0];
    const int*   esrc  = (const int*)  d_in[1];
    const int*   edst  = (const int*)  d_in[2];
    const float* evals = (const float*)d_in[3];
    const float* w     = (const float*)d_in[4];
    const float* bias  = (const float*)d_in[5];
    float* out = (float*)d_out;

    const int n_nodes = in_sizes[0] / DIN;
    const int n_edges = in_sizes[1];

    float* support = (float*)d_ws;   // n_nodes * 64 * 4 B = 12.8 MB

    // out doubles as the segment-sum accumulator: zero it first
    hipMemsetAsync(d_out, 0, (size_t)out_size * sizeof(float), stream);

    // 1) support = X @ W
    gcn_gemm<<<(n_nodes + 15) / 16, 256, 0, stream>>>(x, w, support, n_nodes);

    // 2) out[dst] += support[src] * val   (atomic scatter)
    int sblocks = (n_edges * 16 + 255) / 256;
    gcn_scatter<<<sblocks, 256, 0, stream>>>(support, esrc, edst, evals, out, n_edges);

    // 3) out = elu(out + bias)
    int n4 = out_size / 4;
    gcn_epilogue<<<(n4 + 255) / 256, 256, 0, stream>>>(out, bias, n4);
}

// Round 2
// 271.318 us; speedup vs baseline: 2.6409x; 2.6409x over previous
//
#include <hip/hip_runtime.h>
#include <math.h>

#define DIN 128
#define DOUT 64

// ---------------------------------------------------------------------------
// Kernel 1: support = X @ W   [n x 128] @ [128 x 64] -> [n x 64]
// ---------------------------------------------------------------------------
__global__ __launch_bounds__(256)
void gcn_gemm(const float* __restrict__ x, const float* __restrict__ w,
              float* __restrict__ support, int n_nodes) {
    __shared__ float ws[DIN][DOUT];      // 32 KB
    __shared__ float xs[16][DIN + 4];

    const int t = threadIdx.x;
    const int base = blockIdx.x * 16;

    for (int i = t; i < (DIN * DOUT) / 4; i += 256)
        reinterpret_cast<float4*>(&ws[0][0])[i] =
            reinterpret_cast<const float4*>(w)[i];

    for (int i = t; i < 16 * (DIN / 4); i += 256) {
        int row = i >> 5, kq = i & 31;
        if (base + row < n_nodes) {
            float4 v = reinterpret_cast<const float4*>(x)[
                (size_t)(base + row) * (DIN / 4) + kq];
            *reinterpret_cast<float4*>(&xs[row][kq * 4]) = v;
        }
    }
    __syncthreads();

    const int r = t >> 4;
    const int c = t & 15;

    float4 acc = {0.f, 0.f, 0.f, 0.f};
    #pragma unroll
    for (int k0 = 0; k0 < DIN; k0 += 4) {
        float4 xv = *reinterpret_cast<const float4*>(&xs[r][k0]);
        float4 w0 = *reinterpret_cast<const float4*>(&ws[k0 + 0][c * 4]);
        float4 w1 = *reinterpret_cast<const float4*>(&ws[k0 + 1][c * 4]);
        float4 w2 = *reinterpret_cast<const float4*>(&ws[k0 + 2][c * 4]);
        float4 w3 = *reinterpret_cast<const float4*>(&ws[k0 + 3][c * 4]);
        acc.x += xv.x * w0.x + xv.y * w1.x + xv.z * w2.x + xv.w * w3.x;
        acc.y += xv.x * w0.y + xv.y * w1.y + xv.z * w2.y + xv.w * w3.y;
        acc.z += xv.x * w0.z + xv.y * w1.z + xv.z * w2.z + xv.w * w3.z;
        acc.w += xv.x * w0.w + xv.y * w1.w + xv.z * w2.w + xv.w * w3.w;
    }

    int row = base + r;
    if (row < n_nodes)
        reinterpret_cast<float4*>(support)[(size_t)row * (DOUT / 4) + c] = acc;
}

// ---------------------------------------------------------------------------
// Kernel 2: degree histogram of edge_dst
// ---------------------------------------------------------------------------
__global__ __launch_bounds__(256)
void k_hist(const int* __restrict__ edst, int* __restrict__ deg, int n_edges) {
    int i = blockIdx.x * 256 + threadIdx.x;
    if (i < n_edges) atomicAdd(&deg[edst[i]], 1);
}

// ---------------------------------------------------------------------------
// Kernel 3: single-block exclusive scan: deg[0..n) -> off[0..n], cursor copy
// ---------------------------------------------------------------------------
__global__ __launch_bounds__(1024)
void k_scan(const int* __restrict__ deg, int* __restrict__ off,
            int* __restrict__ cursor, int n) {
    __shared__ int ssum[1024];
    const int t = threadIdx.x;
    const int chunk = (n + 1023) / 1024;
    const int lo = t * chunk;
    const int hi = min(lo + chunk, n);

    int s = 0;
    for (int i = lo; i < hi; i++) s += deg[i];
    ssum[t] = s;
    __syncthreads();

    // Hillis-Steele inclusive scan (read-before-write via barriers)
    for (int d = 1; d < 1024; d <<= 1) {
        int v = (t >= d) ? ssum[t - d] : 0;
        __syncthreads();
        ssum[t] += v;
        __syncthreads();
    }

    int excl = ssum[t] - s;   // exclusive prefix at chunk start
    for (int i = lo; i < hi; i++) {
        off[i] = excl;
        cursor[i] = excl;
        excl += deg[i];
    }
    if (hi == n && lo < n) off[n] = excl;   // total
}

// ---------------------------------------------------------------------------
// Kernel 4: scatter edges into CSR order, packing (src, val) as int2
// ---------------------------------------------------------------------------
__global__ __launch_bounds__(256)
void k_perm(const int* __restrict__ esrc, const int* __restrict__ edst,
            const float* __restrict__ evals, int* __restrict__ cursor,
            int2* __restrict__ perm, int n_edges) {
    int i = blockIdx.x * 256 + threadIdx.x;
    if (i >= n_edges) return;
    int d = edst[i];
    int pos = atomicAdd(&cursor[d], 1);
    perm[pos] = make_int2(esrc[i], __float_as_int(evals[i]));
}

// ---------------------------------------------------------------------------
// Kernel 5: per-node gather-reduce + bias + ELU.  One wave (64 lanes) per
// node; lane = output feature. Each edge read is one coalesced 256B line.
// ---------------------------------------------------------------------------
__global__ __launch_bounds__(256)
void k_gather(const float* __restrict__ support, const int* __restrict__ off,
              const int2* __restrict__ perm, const float* __restrict__ bias,
              float* __restrict__ out, int n_nodes) {
    int wid  = (blockIdx.x * 256 + threadIdx.x) >> 6;   // node id
    int lane = threadIdx.x & 63;                        // feature id
    if (wid >= n_nodes) return;

    int e  = off[wid];
    int e1 = off[wid + 1];

    float acc = 0.f;

    // 8-deep unroll: 8 independent gathers in flight to hide L2/L3 latency
    for (; e + 8 <= e1; e += 8) {
        int2 p[8];
        float a[8];
        #pragma unroll
        for (int j = 0; j < 8; j++) p[j] = perm[e + j];        // broadcast
        #pragma unroll
        for (int j = 0; j < 8; j++)
            a[j] = support[(size_t)p[j].x * DOUT + lane];      // coalesced
        #pragma unroll
        for (int j = 0; j < 8; j++)
            acc += a[j] * __int_as_float(p[j].y);
    }
    for (; e < e1; e++) {
        int2 p = perm[e];
        acc += support[(size_t)p.x * DOUT + lane] * __int_as_float(p.y);
    }

    float v = acc + bias[lane];
    out[(size_t)wid * DOUT + lane] = v > 0.f ? v : expm1f(v);
}

// ---------------------------------------------------------------------------
extern "C" void kernel_launch(void* const* d_in, const int* in_sizes, int n_in,
                              void* d_out, int out_size, void* d_ws, size_t ws_size,
                              hipStream_t stream) {
    const float* x     = (const float*)d_in[0];
    const int*   esrc  = (const int*)  d_in[1];
    const int*   edst  = (const int*)  d_in[2];
    const float* evals = (const float*)d_in[3];
    const float* w     = (const float*)d_in[4];
    const float* bias  = (const float*)d_in[5];
    float* out = (float*)d_out;

    const int n_nodes = in_sizes[0] / DIN;
    const int n_edges = in_sizes[1];

    // workspace layout (256B aligned slices)
    char* p = (char*)d_ws;
    auto alloc = [&](size_t bytes) {
        char* r = p;
        p += (bytes + 255) & ~(size_t)255;
        return r;
    };
    float* support = (float*)alloc((size_t)n_nodes * DOUT * sizeof(float)); // 12.8 MB
    int*   deg     = (int*)  alloc((size_t)n_nodes * sizeof(int));
    int*   off     = (int*)  alloc((size_t)(n_nodes + 1) * sizeof(int));
    int*   cursor  = (int*)  alloc((size_t)n_nodes * sizeof(int));
    int2*  perm    = (int2*) alloc((size_t)n_edges * sizeof(int2));         // 6.4 MB

    // zero the degree histogram (capture-legal)
    hipMemsetAsync(deg, 0, (size_t)n_nodes * sizeof(int), stream);

    // 1) support = X @ W
    gcn_gemm<<<(n_nodes + 15) / 16, 256, 0, stream>>>(x, w, support, n_nodes);

    // 2) CSR build: histogram -> scan -> permute
    k_hist<<<(n_edges + 255) / 256, 256, 0, stream>>>(edst, deg, n_edges);
    k_scan<<<1, 1024, 0, stream>>>(deg, off, cursor, n_nodes);
    k_perm<<<(n_edges + 255) / 256, 256, 0, stream>>>(esrc, edst, evals,
                                                      cursor, perm, n_edges);

    // 3) gather-reduce + bias + ELU (fused epilogue)
    int waves = n_nodes;                       // one wave per node
    int blocks = (waves * 64 + 255) / 256;
    k_gather<<<blocks, 256, 0, stream>>>(support, off, perm, bias, out, n_nodes);
}

// Round 3
// 168.532 us; speedup vs baseline: 4.2516x; 1.6099x over previous
//
#include <hip/hip_runtime.h>
#include <math.h>

#define DIN 128
#define DOUT 64

// ---------------------------------------------------------------------------
// Kernel 1: support = X @ W   [n x 128] @ [128 x 64] -> [n x 64]
// ---------------------------------------------------------------------------
__global__ __launch_bounds__(256)
void gcn_gemm(const float* __restrict__ x, const float* __restrict__ w,
              float* __restrict__ support, int n_nodes) {
    __shared__ float ws[DIN][DOUT];      // 32 KB
    __shared__ float xs[16][DIN + 4];

    const int t = threadIdx.x;
    const int base = blockIdx.x * 16;

    for (int i = t; i < (DIN * DOUT) / 4; i += 256)
        reinterpret_cast<float4*>(&ws[0][0])[i] =
            reinterpret_cast<const float4*>(w)[i];

    for (int i = t; i < 16 * (DIN / 4); i += 256) {
        int row = i >> 5, kq = i & 31;
        if (base + row < n_nodes) {
            float4 v = reinterpret_cast<const float4*>(x)[
                (size_t)(base + row) * (DIN / 4) + kq];
            *reinterpret_cast<float4*>(&xs[row][kq * 4]) = v;
        }
    }
    __syncthreads();

    const int r = t >> 4;
    const int c = t & 15;

    float4 acc = {0.f, 0.f, 0.f, 0.f};
    #pragma unroll
    for (int k0 = 0; k0 < DIN; k0 += 4) {
        float4 xv = *reinterpret_cast<const float4*>(&xs[r][k0]);
        float4 w0 = *reinterpret_cast<const float4*>(&ws[k0 + 0][c * 4]);
        float4 w1 = *reinterpret_cast<const float4*>(&ws[k0 + 1][c * 4]);
        float4 w2 = *reinterpret_cast<const float4*>(&ws[k0 + 2][c * 4]);
        float4 w3 = *reinterpret_cast<const float4*>(&ws[k0 + 3][c * 4]);
        acc.x += xv.x * w0.x + xv.y * w1.x + xv.z * w2.x + xv.w * w3.x;
        acc.y += xv.x * w0.y + xv.y * w1.y + xv.z * w2.y + xv.w * w3.y;
        acc.z += xv.x * w0.z + xv.y * w1.z + xv.z * w2.z + xv.w * w3.z;
        acc.w += xv.x * w0.w + xv.y * w1.w + xv.z * w2.w + xv.w * w3.w;
    }

    int row = base + r;
    if (row < n_nodes)
        reinterpret_cast<float4*>(support)[(size_t)row * (DOUT / 4) + c] = acc;
}

// ---------------------------------------------------------------------------
// Kernel 2: degree histogram of edge_dst
// ---------------------------------------------------------------------------
__global__ __launch_bounds__(256)
void k_hist(const int* __restrict__ edst, int* __restrict__ deg, int n_edges) {
    int i = blockIdx.x * 256 + threadIdx.x;
    if (i < n_edges) atomicAdd(&deg[edst[i]], 1);
}

// ---------------------------------------------------------------------------
// Kernel 3a: per-block exclusive scan of deg; emits local prefix + block sum
// ---------------------------------------------------------------------------
__global__ __launch_bounds__(256)
void k_scan_a(const int* __restrict__ deg, int* __restrict__ off_local,
              int* __restrict__ bsum, int n) {
    __shared__ int s[256];
    const int t = threadIdx.x;
    const int i = blockIdx.x * 256 + t;
    int v = (i < n) ? deg[i] : 0;
    s[t] = v;
    __syncthreads();
    #pragma unroll
    for (int d = 1; d < 256; d <<= 1) {
        int u = (t >= d) ? s[t - d] : 0;
        __syncthreads();
        s[t] += u;
        __syncthreads();
    }
    if (i < n) off_local[i] = s[t] - v;       // exclusive within block
    if (t == 255) bsum[blockIdx.x] = s[255];  // block total
}

// ---------------------------------------------------------------------------
// Kernel 3b: one small block scans the block sums -> exclusive boff
// ---------------------------------------------------------------------------
__global__ __launch_bounds__(256)
void k_scan_b(const int* __restrict__ bsum, int* __restrict__ boff, int nb) {
    __shared__ int s[256];
    const int t = threadIdx.x;
    const int chunk = (nb + 255) / 256;
    const int lo = t * chunk;
    const int hi = min(lo + chunk, nb);
    int sum = 0;
    for (int i = lo; i < hi; i++) sum += bsum[i];
    s[t] = sum;
    __syncthreads();
    #pragma unroll
    for (int d = 1; d < 256; d <<= 1) {
        int u = (t >= d) ? s[t - d] : 0;
        __syncthreads();
        s[t] += u;
        __syncthreads();
    }
    int excl = s[t] - sum;
    for (int i = lo; i < hi; i++) {
        boff[i] = excl;
        excl += bsum[i];
    }
}

// ---------------------------------------------------------------------------
// Kernel 3c: off[i] = off_local[i] + boff[block]; cursor copy; off[n] total
// ---------------------------------------------------------------------------
__global__ __launch_bounds__(256)
void k_scan_c(const int* __restrict__ deg, const int* __restrict__ off_local,
              const int* __restrict__ boff, int* __restrict__ off,
              int* __restrict__ cursor, int n) {
    int i = blockIdx.x * 256 + threadIdx.x;
    if (i >= n) return;
    int o = off_local[i] + boff[i >> 8];
    off[i] = o;
    cursor[i] = o;
    if (i == n - 1) off[n] = o + deg[i];
}

// ---------------------------------------------------------------------------
// Kernel 4: scatter edges into CSR order, packing (src, val) as int2
// ---------------------------------------------------------------------------
__global__ __launch_bounds__(256)
void k_perm(const int* __restrict__ esrc, const int* __restrict__ edst,
            const float* __restrict__ evals, int* __restrict__ cursor,
            int2* __restrict__ perm, int n_edges) {
    int i = blockIdx.x * 256 + threadIdx.x;
    if (i >= n_edges) return;
    int d = edst[i];
    int pos = atomicAdd(&cursor[d], 1);
    perm[pos] = make_int2(esrc[i], __float_as_int(evals[i]));
}

// ---------------------------------------------------------------------------
// Kernel 5: per-node gather-reduce + bias + ELU. One wave per node.
// ---------------------------------------------------------------------------
__global__ __launch_bounds__(256)
void k_gather(const float* __restrict__ support, const int* __restrict__ off,
              const int2* __restrict__ perm, const float* __restrict__ bias,
              float* __restrict__ out, int n_nodes) {
    int wid  = (blockIdx.x * 256 + threadIdx.x) >> 6;   // node id
    int lane = threadIdx.x & 63;                        // feature id
    if (wid >= n_nodes) return;

    int e  = off[wid];
    int e1 = off[wid + 1];

    float acc = 0.f;

    for (; e + 8 <= e1; e += 8) {
        int2 p[8];
        float a[8];
        #pragma unroll
        for (int j = 0; j < 8; j++) p[j] = perm[e + j];        // broadcast
        #pragma unroll
        for (int j = 0; j < 8; j++)
            a[j] = support[(size_t)p[j].x * DOUT + lane];      // coalesced
        #pragma unroll
        for (int j = 0; j < 8; j++)
            acc += a[j] * __int_as_float(p[j].y);
    }
    for (; e < e1; e++) {
        int2 p = perm[e];
        acc += support[(size_t)p.x * DOUT + lane] * __int_as_float(p.y);
    }

    float v = acc + bias[lane];
    out[(size_t)wid * DOUT + lane] = v > 0.f ? v : expm1f(v);
}

// ---------------------------------------------------------------------------
extern "C" void kernel_launch(void* const* d_in, const int* in_sizes, int n_in,
                              void* d_out, int out_size, void* d_ws, size_t ws_size,
                              hipStream_t stream) {
    const float* x     = (const float*)d_in[0];
    const int*   esrc  = (const int*)  d_in[1];
    const int*   edst  = (const int*)  d_in[2];
    const float* evals = (const float*)d_in[3];
    const float* w     = (const float*)d_in[4];
    const float* bias  = (const float*)d_in[5];
    float* out = (float*)d_out;

    const int n_nodes = in_sizes[0] / DIN;
    const int n_edges = in_sizes[1];
    const int nb = (n_nodes + 255) / 256;

    // workspace layout (256B aligned slices)
    char* p = (char*)d_ws;
    auto alloc = [&](size_t bytes) {
        char* r = p;
        p += (bytes + 255) & ~(size_t)255;
        return r;
    };
    float* support   = (float*)alloc((size_t)n_nodes * DOUT * sizeof(float));
    int*   deg       = (int*)  alloc((size_t)n_nodes * sizeof(int));
    int*   off       = (int*)  alloc((size_t)(n_nodes + 1) * sizeof(int));
    int*   cursor    = (int*)  alloc((size_t)n_nodes * sizeof(int));
    int*   off_local = (int*)  alloc((size_t)n_nodes * sizeof(int));
    int*   bsum      = (int*)  alloc((size_t)nb * sizeof(int));
    int*   boff      = (int*)  alloc((size_t)nb * sizeof(int));
    int2*  perm      = (int2*) alloc((size_t)n_edges * sizeof(int2));

    hipMemsetAsync(deg, 0, (size_t)n_nodes * sizeof(int), stream);

    // 1) support = X @ W
    gcn_gemm<<<(n_nodes + 15) / 16, 256, 0, stream>>>(x, w, support, n_nodes);

    // 2) CSR build: histogram -> hierarchical scan -> permute
    k_hist<<<(n_edges + 255) / 256, 256, 0, stream>>>(edst, deg, n_edges);
    k_scan_a<<<nb, 256, 0, stream>>>(deg, off_local, bsum, n_nodes);
    k_scan_b<<<1, 256, 0, stream>>>(bsum, boff, nb);
    k_scan_c<<<nb, 256, 0, stream>>>(deg, off_local, boff, off, cursor, n_nodes);
    k_perm<<<(n_edges + 255) / 256, 256, 0, stream>>>(esrc, edst, evals,
                                                      cursor, perm, n_edges);

    // 3) gather-reduce + bias + ELU
    int blocks = (n_nodes * 64 + 255) / 256;
    k_gather<<<blocks, 256, 0, stream>>>(support, off, perm, bias, out, n_nodes);
}

// Round 4
// 158.712 us; speedup vs baseline: 4.5146x; 1.0619x over previous
//
#include <hip/hip_runtime.h>
#include <math.h>

#define DIN 128
#define DOUT 64
#define NCHAIN 4   // parallel chains per node (ILP on the pointer chase)

// ---------------------------------------------------------------------------
// Kernel 1: support = X @ W   [n x 128] @ [128 x 64] -> [n x 64]
// ---------------------------------------------------------------------------
__global__ __launch_bounds__(256)
void gcn_gemm(const float* __restrict__ x, const float* __restrict__ w,
              float* __restrict__ support, int n_nodes) {
    __shared__ float ws[DIN][DOUT];      // 32 KB
    __shared__ float xs[16][DIN + 4];

    const int t = threadIdx.x;
    const int base = blockIdx.x * 16;

    for (int i = t; i < (DIN * DOUT) / 4; i += 256)
        reinterpret_cast<float4*>(&ws[0][0])[i] =
            reinterpret_cast<const float4*>(w)[i];

    for (int i = t; i < 16 * (DIN / 4); i += 256) {
        int row = i >> 5, kq = i & 31;
        if (base + row < n_nodes) {
            float4 v = reinterpret_cast<const float4*>(x)[
                (size_t)(base + row) * (DIN / 4) + kq];
            *reinterpret_cast<float4*>(&xs[row][kq * 4]) = v;
        }
    }
    __syncthreads();

    const int r = t >> 4;
    const int c = t & 15;

    float4 acc = {0.f, 0.f, 0.f, 0.f};
    #pragma unroll
    for (int k0 = 0; k0 < DIN; k0 += 4) {
        float4 xv = *reinterpret_cast<const float4*>(&xs[r][k0]);
        float4 w0 = *reinterpret_cast<const float4*>(&ws[k0 + 0][c * 4]);
        float4 w1 = *reinterpret_cast<const float4*>(&ws[k0 + 1][c * 4]);
        float4 w2 = *reinterpret_cast<const float4*>(&ws[k0 + 2][c * 4]);
        float4 w3 = *reinterpret_cast<const float4*>(&ws[k0 + 3][c * 4]);
        acc.x += xv.x * w0.x + xv.y * w1.x + xv.z * w2.x + xv.w * w3.x;
        acc.y += xv.x * w0.y + xv.y * w1.y + xv.z * w2.y + xv.w * w3.y;
        acc.z += xv.x * w0.z + xv.y * w1.z + xv.z * w2.z + xv.w * w3.z;
        acc.w += xv.x * w0.w + xv.y * w1.w + xv.z * w2.w + xv.w * w3.w;
    }

    int row = base + r;
    if (row < n_nodes)
        reinterpret_cast<float4*>(support)[(size_t)row * (DOUT / 4) + c] = acc;
}

// ---------------------------------------------------------------------------
// Kernel 2: build per-destination linked lists (NCHAIN chains per node).
// Only sequential writes to rec[]; random traffic is 4B atomicExch in the
// small head[] array (L2-resident). rec packs {next, src, val} in 16B.
// ---------------------------------------------------------------------------
__global__ __launch_bounds__(256)
void k_build(const int* __restrict__ esrc, const int* __restrict__ edst,
             const float* __restrict__ evals, int* __restrict__ head,
             int4* __restrict__ rec, int n_edges) {
    int i = blockIdx.x * 256 + threadIdx.x;
    if (i >= n_edges) return;
    int d = edst[i];
    int prev = atomicExch(&head[NCHAIN * d + (i & (NCHAIN - 1))], i);
    rec[i] = make_int4(prev, esrc[i], __float_as_int(evals[i]), 0);
}

// ---------------------------------------------------------------------------
// Kernel 3: per-node gather-reduce + bias + ELU. One wave (64 lanes) per
// node, lane = feature. Walks NCHAIN chains simultaneously: 4 independent
// pointer chases + 4 feature gathers in flight per iteration.
// ---------------------------------------------------------------------------
__global__ __launch_bounds__(256)
void k_gather(const float* __restrict__ support, const int* __restrict__ head,
              const int4* __restrict__ rec, const float* __restrict__ bias,
              float* __restrict__ out, int n_nodes) {
    int wid  = (blockIdx.x * 256 + threadIdx.x) >> 6;   // node id
    int lane = threadIdx.x & 63;                        // feature id
    if (wid >= n_nodes) return;

    int e0 = head[NCHAIN * wid + 0];
    int e1 = head[NCHAIN * wid + 1];
    int e2 = head[NCHAIN * wid + 2];
    int e3 = head[NCHAIN * wid + 3];

    float a0 = 0.f, a1 = 0.f, a2 = 0.f, a3 = 0.f;

    // all chains done <=> all ids are -1 <=> AND of ids is negative
    while ((e0 & e1 & e2 & e3) >= 0) {
        if (e0 >= 0) {
            int4 r = rec[e0];
            a0 += support[(size_t)r.y * DOUT + lane] * __int_as_float(r.z);
            e0 = r.x;
        }
        if (e1 >= 0) {
            int4 r = rec[e1];
            a1 += support[(size_t)r.y * DOUT + lane] * __int_as_float(r.z);
            e1 = r.x;
        }
        if (e2 >= 0) {
            int4 r = rec[e2];
            a2 += support[(size_t)r.y * DOUT + lane] * __int_as_float(r.z);
            e2 = r.x;
        }
        if (e3 >= 0) {
            int4 r = rec[e3];
            a3 += support[(size_t)r.y * DOUT + lane] * __int_as_float(r.z);
            e3 = r.x;
        }
    }

    float v = ((a0 + a1) + (a2 + a3)) + bias[lane];
    out[(size_t)wid * DOUT + lane] = v > 0.f ? v : expm1f(v);
}

// ---------------------------------------------------------------------------
extern "C" void kernel_launch(void* const* d_in, const int* in_sizes, int n_in,
                              void* d_out, int out_size, void* d_ws, size_t ws_size,
                              hipStream_t stream) {
    const float* x     = (const float*)d_in[0];
    const int*   esrc  = (const int*)  d_in[1];
    const int*   edst  = (const int*)  d_in[2];
    const float* evals = (const float*)d_in[3];
    const float* w     = (const float*)d_in[4];
    const float* bias  = (const float*)d_in[5];
    float* out = (float*)d_out;

    const int n_nodes = in_sizes[0] / DIN;
    const int n_edges = in_sizes[1];

    // workspace layout (256B aligned slices)
    char* p = (char*)d_ws;
    auto alloc = [&](size_t bytes) {
        char* r = p;
        p += (bytes + 255) & ~(size_t)255;
        return r;
    };
    float* support = (float*)alloc((size_t)n_nodes * DOUT * sizeof(float)); // 12.8 MB
    int*   head    = (int*)  alloc((size_t)n_nodes * NCHAIN * sizeof(int)); // 0.8 MB
    int4*  rec     = (int4*) alloc((size_t)n_edges * sizeof(int4));         // 12.8 MB

    // head = -1 everywhere (0xFF bytes == -1 as int)
    hipMemsetAsync(head, 0xFF, (size_t)n_nodes * NCHAIN * sizeof(int), stream);

    // 1) support = X @ W
    gcn_gemm<<<(n_nodes + 15) / 16, 256, 0, stream>>>(x, w, support, n_nodes);

    // 2) linked-list build (sequential writes only)
    k_build<<<(n_edges + 255) / 256, 256, 0, stream>>>(esrc, edst, evals,
                                                       head, rec, n_edges);

    // 3) gather-reduce + bias + ELU
    int blocks = (n_nodes * 64 + 255) / 256;
    k_gather<<<blocks, 256, 0, stream>>>(support, head, rec, bias, out, n_nodes);
}